// Round 2
// baseline (130.345 us; speedup 1.0000x reference)
//
#include <hip/hip_runtime.h>
#include <type_traits>

// SimpleRelativeAttention collapses twice:
// 1. einsum 'bnqk,bnqe->bnqe' multiplies v by softmax row-sums (==1) -> attention
//    is an identity on v. rel_table/rel_index/q/k are dead.
// 2. out = x @ Wv @ Wproj + (b_v @ Wproj + b_proj); fold W_c = Wv @ Wproj
//    (1024^3 mini-GEMM) so the hot path is ONE 4096x1024x1024 GEMM.
// Timed window includes ~86us of harness poison/restore (fillBufferAligned);
// controllable budget ~42us. Round-1 dbuf was neutral -> k-loops are LDS/issue
// bound, not latency-bound, and the window is part dispatch overhead.
// This round: 6 nodes -> 3.
//  - cast kernel DELETED: gemm2 stages x as f32 via global_load_lds (4-float
//    16B chunks, XOR swizzle chunk^ (row&15)) and converts to bf16 per
//    fragment with v_cvt_pk_bf16_f32 (2 f32 -> packed 2xbf16, 1 VALU op).
//    Saves 24 MB HBM (cast rd16+wr8) + one node, costs +8MB f32 fetch in gemm2.
//  - memset node DELETED: prep writes b_cp[32][1024] partials with plain
//    stores; 16 blocks of gemm1 reduce b_cp -> b_c (dispatch-order safe).

#define DIMC 1024
#define MTOT 4096   // BATCH * SEQ

__device__ __forceinline__ unsigned short f2bf(float f) {
  unsigned u = __float_as_uint(f);
  u += 0x7FFFu + ((u >> 16) & 1u);   // round-to-nearest-even
  return (unsigned short)(u >> 16);
}

typedef __attribute__((ext_vector_type(8))) short short8;
typedef __attribute__((ext_vector_type(4))) float floatx4;

__device__ __forceinline__ void async_copy16(const void* g, void* l) {
  __builtin_amdgcn_global_load_lds(
      (const __attribute__((address_space(1))) unsigned int*)g,
      (__attribute__((address_space(3))) unsigned int*)l,
      16, 0, 0);
}

// 8 f32 (two float4, k-consecutive) -> short8 of bf16 via v_cvt_pk_bf16_f32.
// No builtin on gfx950 (learn_hip m240) -> inline asm. Pure, non-volatile.
__device__ __forceinline__ short8 cvt8(floatx4 lo, floatx4 hi) {
  unsigned r0, r1, r2, r3;
  asm("v_cvt_pk_bf16_f32 %0, %1, %2" : "=v"(r0) : "v"(lo[0]), "v"(lo[1]));
  asm("v_cvt_pk_bf16_f32 %0, %1, %2" : "=v"(r1) : "v"(lo[2]), "v"(lo[3]));
  asm("v_cvt_pk_bf16_f32 %0, %1, %2" : "=v"(r2) : "v"(hi[0]), "v"(hi[1]));
  asm("v_cvt_pk_bf16_f32 %0, %1, %2" : "=v"(r3) : "v"(hi[2]), "v"(hi[3]));
  union { unsigned u[4]; short8 s; } u;
  u.u[0] = r0; u.u[1] = r1; u.u[2] = r2; u.u[3] = r3;
  return u.s;
}

// Fused weight prep, grid (32,32) x 256 thr. Block (bx,by):
//  - WpT[n][j] = w_proj[j][n] for j in by-tile, n in bx-tile (LDS transpose)
//  - Wvb[k][j2] = w_qkv[k][2048+j2] for k in by-tile, j2 in bx-tile (cast)
//  - b_cp[by][n] = sum_{j in by-tile} b_v[j] * w_proj[j][n]  (plain store;
//    reduced to b_c by gemm1's first 16 blocks -- no memset, no atomics)
__global__ void prep_kernel(const float* __restrict__ w_proj,
                            const float* __restrict__ w_qkv,
                            const float* __restrict__ b_v,
                            unsigned short* __restrict__ WpT,
                            unsigned short* __restrict__ Wvb,
                            float* __restrict__ b_cp) {
  __shared__ float tile[32][33];
  const int t = threadIdx.x;
  const int tx = t & 31, ty = t >> 5;
  const int bx = blockIdx.x, by = blockIdx.y;
#pragma unroll
  for (int r = 0; r < 4; ++r) {
    int kl = ty + r * 8;
    tile[kl][tx] = w_proj[(size_t)(by * 32 + kl) * DIMC + bx * 32 + tx];
  }
  {  // w_qkv slice cast (independent of LDS)
    const int r2 = t >> 3, c4 = (t & 7) * 4;
    float4 f = *(const float4*)(w_qkv + (size_t)(by * 32 + r2) * (3 * DIMC) +
                                2 * DIMC + bx * 32 + c4);
    ushort4 o;
    o.x = f2bf(f.x); o.y = f2bf(f.y); o.z = f2bf(f.z); o.w = f2bf(f.w);
    *(ushort4*)(Wvb + (size_t)(by * 32 + r2) * DIMC + bx * 32 + c4) = o;
  }
  __syncthreads();
#pragma unroll
  for (int r = 0; r < 4; ++r) {
    int nl = ty + r * 8;
    WpT[(size_t)(bx * 32 + nl) * DIMC + by * 32 + tx] = f2bf(tile[tx][nl]);
  }
  if (t < 32) {
    float s = 0.f;
#pragma unroll
    for (int kl = 0; kl < 32; ++kl) s += b_v[by * 32 + kl] * tile[kl][t];
    b_cp[(size_t)by * DIMC + bx * 32 + t] = s;
  }
}

// C[M,N] = A[M,K] @ Bt[N,K]^T (+ bias[N] + bias2[N])
// BM x BN block tile, BK=64, 256 threads = 4 waves in 2x2, wave tile
// (BM/2)x(BN/2), 16x16x32 bf16 MFMA, double-buffered LDS + prefetch, one
// raw s_barrier + vmcnt(0) per k-step.
// A path:
//  - AF32=false: A is bf16 [M,K]; 16B = 8-elem k-chunks, global-side XOR
//    swizzle (tid&7)^(row&7); fragment read kphys = ((s*4+qr)^(lr&7))*8.
//  - AF32=true:  A is f32 [M,K] (x read directly, no cast kernel); 16B =
//    4-float chunks, 16 chunks/row of 256B, XOR swizzle chunk^(row&15).
//    Fragment: two ds_read_b128 at chunks (2*(s*4+qr)+h)^lr, then cvt8().
//    Bank check: quad = chunk&7 -> 8 lanes per 16B quad = b128 minimum.
// gemm1 extra duty: blocks 0..15 reduce b_cp[32][1024] -> b_c after epilogue.
// SWZ: XCD-aware 1D-grid decode (speed heuristic only).
template <int BM, int BN, bool AF32, bool BF16_OUT, bool SWZ>
__global__ __launch_bounds__(256) void gemm_bt_kernel(
    const void* __restrict__ A,             // [M,K] bf16 or f32
    const unsigned short* __restrict__ Bt,  // [N,K] bf16
    const float* __restrict__ bias,         // [N] or nullptr
    const float* __restrict__ bias2,        // [N] or nullptr
    void* __restrict__ Cout, int M, int N, int K, int gx,
    const float* __restrict__ bcp,          // [32,1024] partials or nullptr
    float* __restrict__ bcred) {            // [1024] reduced or nullptr
  using AT = typename std::conditional<AF32, float, unsigned short>::type;
  constexpr int MI = BM / 32;   // m-frags per wave
  constexpr int NI = BN / 32;   // n-frags per wave
  constexpr int AG = AF32 ? BM / 16 : BM / 32;  // A staging glls per thread
  constexpr int BG = BN / 32;                   // B staging glls per thread
  constexpr int ASZ = BM * 64 * (AF32 ? 4 : 2); // A buffer bytes
  __shared__ __align__(16) char Asb[2][ASZ];
  __shared__ __align__(16) unsigned short Bs[2][BN * 64];

  const AT* Ap = (const AT*)A;
  const int tid = threadIdx.x;
  const int wv = tid >> 6;
  const int lane = tid & 63;

  int bx, by;
  if (SWZ) {  // 256 blocks: xcd = bid&7 gets x=all, y in [4*xcd, 4*xcd+4)
    const int bid = blockIdx.x;
    bx = (bid >> 3) & 7;
    by = (bid & 7) * 4 + (bid >> 6);
  } else {
    bx = blockIdx.x % gx;
    by = blockIdx.x / gx;
  }
  const int m0 = by * BM;
  const int n0 = bx * BN;

  floatx4 acc[MI][NI] = {};

  // staging addresses (global-side swizzle; dest is linear base+lane*16)
  const AT* Ag[AG];
  if constexpr (AF32) {
    const int srow = tid >> 4;                 // 0..15 within 16-row group
    const int skc = (tid & 15) ^ srow;         // swizzled 4-float chunk
#pragma unroll
    for (int g = 0; g < AG; ++g)
      Ag[g] = Ap + (size_t)(m0 + g * 16 + srow) * K + skc * 4;
  } else {
    const int srow = tid >> 3;                 // 0..31
    const int skc = (tid & 7) ^ (srow & 7);    // swizzled 8-bf16 chunk
#pragma unroll
    for (int g = 0; g < AG; ++g)
      Ag[g] = Ap + (size_t)(m0 + g * 32 + srow) * K + skc * 8;
  }
  const unsigned short* Bg[BG];
  {
    const int srow = tid >> 3;
    const int skc = (tid & 7) ^ (srow & 7);
#pragma unroll
    for (int g = 0; g < BG; ++g)
      Bg[g] = Bt + (size_t)(n0 + g * 32 + srow) * K + skc * 8;
  }

  const int lr = lane & 15;
  const int qr = lane >> 4;
  const int lx = lr & 7;                     // bf16 fragment-read swizzle key
  const int wrow = (wv >> 1) * (BM / 2);
  const int wcol = (wv & 1) * (BN / 2);

  const int NT = K >> 6;                     // k-tiles (16 for K=1024)

  // prologue: stage tile 0, drain, barrier
#pragma unroll
  for (int g = 0; g < AG; ++g)
    async_copy16(Ag[g], Asb[0] + g * 4096 + wv * 1024);
#pragma unroll
  for (int g = 0; g < BG; ++g)
    async_copy16(Bg[g], (char*)Bs[0] + g * 4096 + wv * 1024);
  asm volatile("s_waitcnt vmcnt(0)" ::: "memory");
  __builtin_amdgcn_s_barrier();

  int cur = 0;
  for (int t = 0; t < NT; ++t) {
    const char* Asc = Asb[cur];
    const unsigned short* Bsc = Bs[cur];
    const bool pre = (t + 1 < NT);
    if (pre) {  // issue prefetch of tile t+1 into the other buffer
      const int nxt = cur ^ 1;
      const int kn = (t + 1) * 64;
#pragma unroll
      for (int g = 0; g < AG; ++g)
        async_copy16(Ag[g] + kn, Asb[nxt] + g * 4096 + wv * 1024);
#pragma unroll
      for (int g = 0; g < BG; ++g)
        async_copy16(Bg[g] + kn, (char*)Bs[nxt] + g * 4096 + wv * 1024);
    }

    short8 a[2][MI], b[2][NI];
#pragma unroll
    for (int s = 0; s < 2; ++s) {
#pragma unroll
      for (int mi = 0; mi < MI; ++mi) {
        const int row = wrow + mi * 16 + lr;
        if constexpr (AF32) {
          const float* Afl = (const float*)Asc;
          const int c0 = (s * 4 + qr) * 2;
          floatx4 lo = *(const floatx4*)(Afl + row * 64 + ((c0 ^ lr) * 4));
          floatx4 hi = *(const floatx4*)(Afl + row * 64 + (((c0 + 1) ^ lr) * 4));
          a[s][mi] = cvt8(lo, hi);
        } else {
          const unsigned short* Au = (const unsigned short*)Asc;
          const int kphys = ((s * 4 + qr) ^ lx) * 8;
          a[s][mi] = *(const short8*)(Au + row * 64 + kphys);
        }
      }
      const int kphysb = ((s * 4 + qr) ^ lx) * 8;
#pragma unroll
      for (int ni = 0; ni < NI; ++ni)
        b[s][ni] = *(const short8*)(Bsc + (wcol + ni * 16 + lr) * 64 + kphysb);
    }
#pragma unroll
    for (int s = 0; s < 2; ++s)
#pragma unroll
      for (int mi = 0; mi < MI; ++mi)
#pragma unroll
        for (int ni = 0; ni < NI; ++ni)
          acc[mi][ni] = __builtin_amdgcn_mfma_f32_16x16x32_bf16(a[s][mi], b[s][ni],
                                                                acc[mi][ni], 0, 0, 0);
    if (pre) {
      // one drain+barrier per k-step: next tile resident AND every wave done
      // reading buf[cur] before it is overwritten at t+1
      asm volatile("s_waitcnt vmcnt(0)" ::: "memory");
      __builtin_amdgcn_s_barrier();
    }
    cur ^= 1;
  }

  // epilogue: C row = m0+wrow+mi*16+qr*4+r, col = n0+wcol+ni*16+lr
#pragma unroll
  for (int mi = 0; mi < MI; ++mi) {
#pragma unroll
    for (int ni = 0; ni < NI; ++ni) {
      const int col = n0 + wcol + ni * 16 + lr;
      float bv = 0.0f;
      if (bias)  bv += bias[col];
      if (bias2) bv += bias2[col];
#pragma unroll
      for (int r = 0; r < 4; ++r) {
        const int row = m0 + wrow + mi * 16 + qr * 4 + r;
        const float val = acc[mi][ni][r] + bv;
        if (BF16_OUT)
          ((unsigned short*)Cout)[(size_t)row * N + col] = f2bf(val);
        else
          ((float*)Cout)[(size_t)row * N + col] = val;
      }
    }
  }

  // b_cp -> b_c reduction (gemm1 only; runs after prep by dispatch order)
  if (bcp) {
    if (blockIdx.x < 16 && tid < 64) {
      const int col = blockIdx.x * 64 + tid;
      float ssum = 0.f;
#pragma unroll
      for (int p = 0; p < 32; ++p) ssum += bcp[p * DIMC + col];
      bcred[col] = ssum;
    }
  }
}

extern "C" void kernel_launch(void* const* d_in, const int* in_sizes, int n_in,
                              void* d_out, int out_size, void* d_ws, size_t ws_size,
                              hipStream_t stream) {
  const float* x      = (const float*)d_in[0];  // [4,1024,1024]
  const float* w_qkv  = (const float*)d_in[1];  // [1024,3072]
  const float* b_qkv  = (const float*)d_in[2];  // [3072]
  const float* w_proj = (const float*)d_in[3];  // [1024,1024]
  const float* b_proj = (const float*)d_in[4];  // [1024]
  // d_in[5]=rel_table, d_in[6]=rel_index unused (softmax rows sum to 1).
  float* out = (float*)d_out;

  char* ws = (char*)d_ws;
  unsigned short* WpT = (unsigned short*)(ws);                      // 2 MB WpT[n][j]=w_proj[j][n]
  unsigned short* Wvb = (unsigned short*)(ws + (size_t)(2u << 20)); // 2 MB Wvb[k][j]=w_qkv[k][2048+j]
  unsigned short* WcT = (unsigned short*)(ws + (size_t)(4u << 20)); // 2 MB WcT[n][k]=W_c[k][n]
  float*          b_cp= (float*)(ws + (size_t)(6u << 20));          // 128 KB partials
  float*          b_c = (float*)(ws + (size_t)(6u << 20) + 131072); // 4 KB

  // 1. fused: WpT transpose-cast, Wvb slice-cast, b_cp partial matvec
  prep_kernel<<<dim3(32, 32), 256, 0, stream>>>(w_proj, w_qkv, b_qkv + 2 * DIMC,
                                                WpT, Wvb, b_cp);
  // 2. WcT[n][k] = sum_j WpT[n][j] * Wvb[k][j] (64x64 tile) + b_cp->b_c reduce
  gemm_bt_kernel<64, 64, false, true, false><<<256, 256, 0, stream>>>(
      WpT, Wvb, nullptr, nullptr, WcT, DIMC, DIMC, DIMC, DIMC / 64, b_cp, b_c);
  // 3. out = x @ WcT^T + (b_c + b_proj); x read as f32, cvt in-fragment
  gemm_bt_kernel<128, 128, true, false, true><<<256, 256, 0, stream>>>(
      x, WcT, b_c, b_proj, out, MTOT, DIMC, DIMC, DIMC / 128, nullptr, nullptr);
}

// Round 3
// 128.391 us; speedup vs baseline: 1.0152x; 1.0152x over previous
//
#include <hip/hip_runtime.h>
#include <type_traits>

// SimpleRelativeAttention collapses twice:
// 1. einsum 'bnqk,bnqe->bnqe' multiplies v by softmax row-sums (==1) -> attention
//    is an identity on v. rel_table/rel_index/q/k are dead.
// 2. out = x @ Wv @ Wproj + (b_v @ Wproj + b_proj); fold W_c = Wv @ Wproj
//    (1024^3 mini-GEMM) so the hot path is ONE 4096x1024x1024 GEMM.
//
// Window model: harness poisons the fixed 256 MiB workspace with ~43us
// HBM-bound fills (WRITE_SIZE=256MiB exactly, independent of our usage).
// R0(6-node)=128.4, R1(dbuf)=129.7, R2(3-node,-24MB)=130.3 -- all within the
// fill-noise band. Either (A) 2 fills + ~42us serial chain, or (B) 3 fills =
// the whole window. This round distinguishes: fix gemm2's f32-A regression
// (R2 doubled A-side LDS reads + in-loop cvt). A is now REG-STAGED:
// global f32 -> v_cvt_pk_bf16_f32 -> swizzled ds_write_b128, so LDS holds
// bf16 (R0 layout, 8 ds_read_b128/lane/k-step) and cvt happens once per
// element instead of twice. If dur doesn't move again -> Model B -> roofline.

#define DIMC 1024
#define MTOT 4096   // BATCH * SEQ

__device__ __forceinline__ unsigned short f2bf(float f) {
  unsigned u = __float_as_uint(f);
  u += 0x7FFFu + ((u >> 16) & 1u);   // round-to-nearest-even
  return (unsigned short)(u >> 16);
}

typedef __attribute__((ext_vector_type(8))) short short8;
typedef __attribute__((ext_vector_type(4))) float floatx4;

__device__ __forceinline__ void async_copy16(const void* g, void* l) {
  __builtin_amdgcn_global_load_lds(
      (const __attribute__((address_space(1))) unsigned int*)g,
      (__attribute__((address_space(3))) unsigned int*)l,
      16, 0, 0);
}

// 8 f32 (two float4, k-consecutive) -> short8 of bf16 via v_cvt_pk_bf16_f32.
// No builtin on gfx950 (learn_hip m240) -> inline asm. Pure, non-volatile.
__device__ __forceinline__ short8 cvt8(floatx4 lo, floatx4 hi) {
  unsigned r0, r1, r2, r3;
  asm("v_cvt_pk_bf16_f32 %0, %1, %2" : "=v"(r0) : "v"(lo[0]), "v"(lo[1]));
  asm("v_cvt_pk_bf16_f32 %0, %1, %2" : "=v"(r1) : "v"(lo[2]), "v"(lo[3]));
  asm("v_cvt_pk_bf16_f32 %0, %1, %2" : "=v"(r2) : "v"(hi[0]), "v"(hi[1]));
  asm("v_cvt_pk_bf16_f32 %0, %1, %2" : "=v"(r3) : "v"(hi[2]), "v"(hi[3]));
  union { unsigned u[4]; short8 s; } u;
  u.u[0] = r0; u.u[1] = r1; u.u[2] = r2; u.u[3] = r3;
  return u.s;
}

// Fused weight prep, grid (32,32) x 256 thr. Block (bx,by):
//  - WpT[n][j] = w_proj[j][n] for j in by-tile, n in bx-tile (LDS transpose)
//  - Wvb[k][j2] = w_qkv[k][2048+j2] for k in by-tile, j2 in bx-tile (cast)
//  - b_cp[by][n] = sum_{j in by-tile} b_v[j] * w_proj[j][n]  (plain store;
//    reduced to b_c by gemm1's first 16 blocks -- no memset, no atomics)
__global__ void prep_kernel(const float* __restrict__ w_proj,
                            const float* __restrict__ w_qkv,
                            const float* __restrict__ b_v,
                            unsigned short* __restrict__ WpT,
                            unsigned short* __restrict__ Wvb,
                            float* __restrict__ b_cp) {
  __shared__ float tile[32][33];
  const int t = threadIdx.x;
  const int tx = t & 31, ty = t >> 5;
  const int bx = blockIdx.x, by = blockIdx.y;
#pragma unroll
  for (int r = 0; r < 4; ++r) {
    int kl = ty + r * 8;
    tile[kl][tx] = w_proj[(size_t)(by * 32 + kl) * DIMC + bx * 32 + tx];
  }
  {  // w_qkv slice cast (independent of LDS)
    const int r2 = t >> 3, c4 = (t & 7) * 4;
    float4 f = *(const float4*)(w_qkv + (size_t)(by * 32 + r2) * (3 * DIMC) +
                                2 * DIMC + bx * 32 + c4);
    ushort4 o;
    o.x = f2bf(f.x); o.y = f2bf(f.y); o.z = f2bf(f.z); o.w = f2bf(f.w);
    *(ushort4*)(Wvb + (size_t)(by * 32 + r2) * DIMC + bx * 32 + c4) = o;
  }
  __syncthreads();
#pragma unroll
  for (int r = 0; r < 4; ++r) {
    int nl = ty + r * 8;
    WpT[(size_t)(bx * 32 + nl) * DIMC + by * 32 + tx] = f2bf(tile[tx][nl]);
  }
  if (t < 32) {
    float s = 0.f;
#pragma unroll
    for (int kl = 0; kl < 32; ++kl) s += b_v[by * 32 + kl] * tile[kl][t];
    b_cp[(size_t)by * DIMC + bx * 32 + t] = s;
  }
}

// C[M,N] = A[M,K] @ Bt[N,K]^T (+ bias[N] + bias2[N])
// BM x BN block tile, BK=64, 256 threads = 4 waves in 2x2, wave tile
// (BM/2)x(BN/2), 16x16x32 bf16 MFMA, double-buffered bf16 LDS + prefetch.
// LDS layout (both operands, both A-paths): [row][physchunk] bf16, 8-elem
// chunks, where LDS[row][p] holds logical k-chunk p^(row&7). Fragment read
// kphys = ((s*4+qr)^(lr&7))*8 is then bank-conflict-free (row&7==lr&7 since
// wrow, mi*16 are multiples of 8).
// A staging:
//  - AF32=false: bf16 source, global_load_lds w16, global-side swizzle
//    (logical chunk = (tid&7)^(row&7), linear LDS dest).
//  - AF32=true: f32 source (x read directly, no cast kernel): per k-step
//    each thread loads 8 consecutive f32 (2x dwordx4, fully coalesced),
//    cvt8 -> ds_write_b128 at phys = (tid&7)^(row&7). Loads issued at
//    k-step start (fly under MFMA), cvt+write after MFMA, __syncthreads.
//    Write banks depend only on phys (row*128B = 0 mod 32 banks) -> uniform
//    8/bank = the b128 minimum, same as linear.
// gemm1 extra duty: blocks 0..15 reduce b_cp[32][1024] -> b_c after epilogue.
// SWZ: XCD-aware 1D-grid decode (speed heuristic only).
template <int BM, int BN, bool AF32, bool BF16_OUT, bool SWZ>
__global__ __launch_bounds__(256) void gemm_bt_kernel(
    const void* __restrict__ A,             // [M,K] bf16 or f32
    const unsigned short* __restrict__ Bt,  // [N,K] bf16
    const float* __restrict__ bias,         // [N] or nullptr
    const float* __restrict__ bias2,        // [N] or nullptr
    void* __restrict__ Cout, int M, int N, int K, int gx,
    const float* __restrict__ bcp,          // [32,1024] partials or nullptr
    float* __restrict__ bcred) {            // [1024] reduced or nullptr
  constexpr int MI = BM / 32;   // m-frags per wave
  constexpr int NI = BN / 32;   // n-frags per wave
  constexpr int AG = BM / 32;   // A staging groups per thread (32 rows each)
  constexpr int BG = BN / 32;   // B staging glls per thread
  __shared__ __align__(16) unsigned short As[2][BM * 64];
  __shared__ __align__(16) unsigned short Bs[2][BN * 64];

  const int tid = threadIdx.x;
  const int wv = tid >> 6;
  const int lane = tid & 63;

  int bx, by;
  if (SWZ) {  // 256 blocks: xcd = bid&7 gets x=all, y in [4*xcd, 4*xcd+4)
    const int bid = blockIdx.x;
    bx = (bid >> 3) & 7;
    by = (bid & 7) * 4 + (bid >> 6);
  } else {
    bx = blockIdx.x % gx;
    by = blockIdx.x / gx;
  }
  const int m0 = by * BM;
  const int n0 = bx * BN;

  floatx4 acc[MI][NI] = {};

  const int srow = tid >> 3;                 // 0..31
  const int sc = tid & 7;                    // chunk slot
  const int sx = srow & 7;                   // row swizzle key

  // A staging addresses
  const float* Agf[AG];          // AF32: contiguous 8-f32 read per group
  const unsigned short* Agb[AG]; // bf16: gll source (swizzled logical chunk)
  unsigned short* Awr[AG];       // AF32: swizzled LDS dest (offset into buf)
  if constexpr (AF32) {
    const float* Ap = (const float*)A;
#pragma unroll
    for (int g = 0; g < AG; ++g) {
      Agf[g] = Ap + (size_t)(m0 + g * 32 + srow) * K + sc * 8;
      Awr[g] = (unsigned short*)0 + (g * 32 + srow) * 64 + (sc ^ sx) * 8;
    }
  } else {
    const unsigned short* Ap = (const unsigned short*)A;
#pragma unroll
    for (int g = 0; g < AG; ++g)
      Agb[g] = Ap + (size_t)(m0 + g * 32 + srow) * K + (sc ^ sx) * 8;
  }
  const unsigned short* Bg[BG];
#pragma unroll
  for (int g = 0; g < BG; ++g)
    Bg[g] = Bt + (size_t)(n0 + g * 32 + srow) * K + (sc ^ sx) * 8;

  const int lr = lane & 15;
  const int qr = lane >> 4;
  const int lx = lr & 7;                     // fragment-read swizzle key
  const int wrow = (wv >> 1) * (BM / 2);
  const int wcol = (wv & 1) * (BN / 2);

  const int NT = K >> 6;                     // k-tiles (16 for K=1024)

  // prologue: stage tile 0
  if constexpr (AF32) {
#pragma unroll
    for (int g = 0; g < AG; ++g) {
      floatx4 lo = *(const floatx4*)(Agf[g]);
      floatx4 hi = *(const floatx4*)(Agf[g] + 4);
      *(short8*)(As[0] + (size_t)(Awr[g] - (unsigned short*)0)) = cvt8(lo, hi);
    }
  } else {
#pragma unroll
    for (int g = 0; g < AG; ++g)
      async_copy16(Agb[g], (char*)As[0] + g * 4096 + wv * 1024);
  }
#pragma unroll
  for (int g = 0; g < BG; ++g)
    async_copy16(Bg[g], (char*)Bs[0] + g * 4096 + wv * 1024);
  __syncthreads();   // drains vmcnt + lgkmcnt

  int cur = 0;
  for (int t = 0; t < NT; ++t) {
    const unsigned short* Asc = As[cur];
    const unsigned short* Bsc = Bs[cur];
    const bool pre = (t + 1 < NT);
    const int nxt = cur ^ 1;
    const int kn = (t + 1) * 64;

    floatx4 alo[AG], ahi[AG];
    if (pre) {  // issue prefetch of tile t+1
      if constexpr (AF32) {
#pragma unroll
        for (int g = 0; g < AG; ++g) {   // loads fly under the MFMAs below
          alo[g] = *(const floatx4*)(Agf[g] + kn);
          ahi[g] = *(const floatx4*)(Agf[g] + kn + 4);
        }
      } else {
#pragma unroll
        for (int g = 0; g < AG; ++g)
          async_copy16(Agb[g] + kn, (char*)As[nxt] + g * 4096 + wv * 1024);
      }
#pragma unroll
      for (int g = 0; g < BG; ++g)
        async_copy16(Bg[g] + kn, (char*)Bs[nxt] + g * 4096 + wv * 1024);
    }

    short8 a[2][MI], b[2][NI];
#pragma unroll
    for (int s = 0; s < 2; ++s) {
      const int kphys = ((s * 4 + qr) ^ lx) * 8;
#pragma unroll
      for (int mi = 0; mi < MI; ++mi)
        a[s][mi] = *(const short8*)(Asc + (wrow + mi * 16 + lr) * 64 + kphys);
#pragma unroll
      for (int ni = 0; ni < NI; ++ni)
        b[s][ni] = *(const short8*)(Bsc + (wcol + ni * 16 + lr) * 64 + kphys);
    }
#pragma unroll
    for (int s = 0; s < 2; ++s)
#pragma unroll
      for (int mi = 0; mi < MI; ++mi)
#pragma unroll
        for (int ni = 0; ni < NI; ++ni)
          acc[mi][ni] = __builtin_amdgcn_mfma_f32_16x16x32_bf16(a[s][mi], b[s][ni],
                                                                acc[mi][ni], 0, 0, 0);
    if (pre) {
      if constexpr (AF32) {  // convert + write A tile t+1 (dataflow waits loads)
#pragma unroll
        for (int g = 0; g < AG; ++g)
          *(short8*)(As[nxt] + (size_t)(Awr[g] - (unsigned short*)0)) =
              cvt8(alo[g], ahi[g]);
      }
      // one barrier per k-step: drains B glls (vmcnt) + A ds_writes (lgkm);
      // next tile resident AND all waves done reading buf[cur]
      __syncthreads();
    }
    cur ^= 1;
  }

  // epilogue: C row = m0+wrow+mi*16+qr*4+r, col = n0+wcol+ni*16+lr
#pragma unroll
  for (int mi = 0; mi < MI; ++mi) {
#pragma unroll
    for (int ni = 0; ni < NI; ++ni) {
      const int col = n0 + wcol + ni * 16 + lr;
      float bv = 0.0f;
      if (bias)  bv += bias[col];
      if (bias2) bv += bias2[col];
#pragma unroll
      for (int r = 0; r < 4; ++r) {
        const int row = m0 + wrow + mi * 16 + qr * 4 + r;
        const float val = acc[mi][ni][r] + bv;
        if (BF16_OUT)
          ((unsigned short*)Cout)[(size_t)row * N + col] = f2bf(val);
        else
          ((float*)Cout)[(size_t)row * N + col] = val;
      }
    }
  }

  // b_cp -> b_c reduction (gemm1 only; runs after prep by dispatch order)
  if (bcp) {
    if (blockIdx.x < 16 && tid < 64) {
      const int col = blockIdx.x * 64 + tid;
      float ssum = 0.f;
#pragma unroll
      for (int p = 0; p < 32; ++p) ssum += bcp[p * DIMC + col];
      bcred[col] = ssum;
    }
  }
}

extern "C" void kernel_launch(void* const* d_in, const int* in_sizes, int n_in,
                              void* d_out, int out_size, void* d_ws, size_t ws_size,
                              hipStream_t stream) {
  const float* x      = (const float*)d_in[0];  // [4,1024,1024]
  const float* w_qkv  = (const float*)d_in[1];  // [1024,3072]
  const float* b_qkv  = (const float*)d_in[2];  // [3072]
  const float* w_proj = (const float*)d_in[3];  // [1024,1024]
  const float* b_proj = (const float*)d_in[4];  // [1024]
  // d_in[5]=rel_table, d_in[6]=rel_index unused (softmax rows sum to 1).
  float* out = (float*)d_out;

  char* ws = (char*)d_ws;
  unsigned short* WpT = (unsigned short*)(ws);                      // 2 MB WpT[n][j]=w_proj[j][n]
  unsigned short* Wvb = (unsigned short*)(ws + (size_t)(2u << 20)); // 2 MB Wvb[k][j]=w_qkv[k][2048+j]
  unsigned short* WcT = (unsigned short*)(ws + (size_t)(4u << 20)); // 2 MB WcT[n][k]=W_c[k][n]
  float*          b_cp= (float*)(ws + (size_t)(6u << 20));          // 128 KB partials
  float*          b_c = (float*)(ws + (size_t)(6u << 20) + 131072); // 4 KB

  // 1. fused: WpT transpose-cast, Wvb slice-cast, b_cp partial matvec
  prep_kernel<<<dim3(32, 32), 256, 0, stream>>>(w_proj, w_qkv, b_qkv + 2 * DIMC,
                                                WpT, Wvb, b_cp);
  // 2. WcT[n][k] = sum_j WpT[n][j] * Wvb[k][j] (64x64 tile) + b_cp->b_c reduce
  gemm_bt_kernel<64, 64, false, true, false><<<256, 256, 0, stream>>>(
      WpT, Wvb, nullptr, nullptr, WcT, DIMC, DIMC, DIMC, DIMC / 64, b_cp, b_c);
  // 3. out = x @ WcT^T + (b_c + b_proj); x reg-staged f32->bf16 at LDS write
  gemm_bt_kernel<128, 128, true, false, true><<<256, 256, 0, stream>>>(
      x, WcT, b_c, b_proj, out, MTOT, DIMC, DIMC, DIMC / 128, nullptr, nullptr);
}